// Round 1
// baseline (122.633 us; speedup 1.0000x reference)
//
#include <hip/hip_runtime.h>
#include <math.h>

// Problem shape (fixed by setup_inputs): B=4, N=M=4096, D=3, fp32.
#define BATCH 4
#define NPTS  4096
#define SEGS  4                  // m-dimension split -> 512 blocks total = 2/CU
#define SEG_LEN (NPTS / SEGS)    // 1024 points staged in LDS per block
#define RPB   256                // threads per block == rows per block

// Each block: one (direction, batch, row-chunk, m-segment).
// Thread t owns row n = rowChunk*256 + t; loops over the LDS-staged segment of
// the opposing set computing min squared distance. All threads read the same
// LDS element each iteration -> broadcast, conflict-free. SoA layout lets the
// unrolled loop vectorize LDS reads (consecutive j -> ds_read_b128).
__global__ __launch_bounds__(RPB) void ahd_min_kernel(
    const float* __restrict__ set1, const float* __restrict__ set2,
    unsigned int* __restrict__ mins /* [2][BATCH][NPTS], uint-ordered f32 */)
{
    const int dir      = blockIdx.z;
    const int b        = blockIdx.y;
    const int rowChunk = blockIdx.x / SEGS;
    const int seg      = blockIdx.x % SEGS;

    const float* __restrict__ X = dir ? set2 : set1;
    const float* __restrict__ Y = dir ? set1 : set2;

    __shared__ float y0s[SEG_LEN];
    __shared__ float y1s[SEG_LEN];
    __shared__ float y2s[SEG_LEN];

    // Stage the Y segment (AoS global -> SoA LDS). 12 KB, one-time cost.
    const float* ybase = Y + ((size_t)b * NPTS + (size_t)seg * SEG_LEN) * 3;
    for (int i = threadIdx.x; i < SEG_LEN; i += RPB) {
        y0s[i] = ybase[i * 3 + 0];
        y1s[i] = ybase[i * 3 + 1];
        y2s[i] = ybase[i * 3 + 2];
    }
    __syncthreads();

    const int n = rowChunk * RPB + threadIdx.x;
    const float* xp = X + ((size_t)b * NPTS + n) * 3;
    const float x0 = xp[0], x1 = xp[1], x2 = xp[2];

    float m = 3.4e38f;
    #pragma unroll 8
    for (int j = 0; j < SEG_LEN; ++j) {
        const float dx = x0 - y0s[j];
        const float dy = x1 - y1s[j];
        const float dz = x2 - y2s[j];
        const float d2 = fmaf(dx, dx, fmaf(dy, dy, dz * dz));
        m = fminf(m, d2);
    }

    // For non-negative floats, the uint bit pattern preserves ordering.
    atomicMin(&mins[(size_t)dir * BATCH * NPTS + (size_t)b * NPTS + n],
              __float_as_uint(m));
}

// Single block: sqrt the 2*B*N mins, sum, normalize.
// With N == M: mean_b(term1 + term2) = (sum of all sqrt mins) / (B*N).
__global__ __launch_bounds__(256) void ahd_reduce_kernel(
    const unsigned int* __restrict__ mins, float* __restrict__ out)
{
    const int total = 2 * BATCH * NPTS;
    float s = 0.f;
    for (int i = threadIdx.x; i < total; i += 256)
        s += sqrtf(__uint_as_float(mins[i]));

    #pragma unroll
    for (int off = 32; off > 0; off >>= 1)
        s += __shfl_down(s, off, 64);

    __shared__ float ws[4];
    const int lane = threadIdx.x & 63;
    const int w    = threadIdx.x >> 6;
    if (lane == 0) ws[w] = s;
    __syncthreads();
    if (threadIdx.x == 0) {
        const float t = ws[0] + ws[1] + ws[2] + ws[3];
        out[0] = t * (1.0f / (float)(BATCH * NPTS));
    }
}

extern "C" void kernel_launch(void* const* d_in, const int* in_sizes, int n_in,
                              void* d_out, int out_size, void* d_ws, size_t ws_size,
                              hipStream_t stream) {
    const float* set1 = (const float*)d_in[0];
    const float* set2 = (const float*)d_in[1];
    float* out = (float*)d_out;
    unsigned int* mins = (unsigned int*)d_ws;   // 2*BATCH*NPTS uints = 128 KB

    const size_t min_bytes = (size_t)2 * BATCH * NPTS * sizeof(unsigned int);
    // 0xFFFFFFFF == uint max -> acts as +inf for the uint atomicMin.
    hipMemsetAsync(mins, 0xFF, min_bytes, stream);

    dim3 grid((NPTS / RPB) * SEGS, BATCH, 2);
    ahd_min_kernel<<<grid, dim3(RPB), 0, stream>>>(set1, set2, mins);
    ahd_reduce_kernel<<<1, dim3(256), 0, stream>>>(mins, out);
}

// Round 2
// 27.334 us; speedup vs baseline: 4.4865x; 4.4865x over previous
//
#include <hip/hip_runtime.h>
#include <math.h>

// Problem shape (fixed by setup_inputs): B=4, N=M=4096, D=3, fp32.
#define BATCH 4
#define NPTS  4096
#define RPB   256                 // threads per block
#define ROWS  4                   // rows (X points) per thread
#define ROWS_PER_BLOCK (RPB * ROWS)          // 1024
#define CHUNKS (NPTS / ROWS_PER_BLOCK)       // 4 row-chunks
#define SEGS  32                  // m-dimension split -> 4*32*4*2 = 1024 blocks (4/CU)
#define SEG_LEN (NPTS / SEGS)     // 128 Y points staged per block

// Gram-form min: for row x, min_j ||x-y_j||^2 = |x|^2 + min_j (|y_j|^2 - 2 x.y_j).
// Inner loop per (row, y): 3 FMA + 1 fmin on a broadcast float4 {y0,y1,y2,|y|^2}.
__global__ __launch_bounds__(RPB) void ahd_min_kernel(
    const float* __restrict__ set1, const float* __restrict__ set2,
    unsigned int* __restrict__ mins /* [2][BATCH][NPTS], uint-ordered f32 d^2 */)
{
    const int dir      = blockIdx.z;
    const int b        = blockIdx.y;
    const int rowChunk = blockIdx.x / SEGS;
    const int seg      = blockIdx.x % SEGS;

    const float* __restrict__ X = dir ? set2 : set1;
    const float* __restrict__ Y = dir ? set1 : set2;

    __shared__ float4 ys[SEG_LEN];   // {y0, y1, y2, |y|^2}

    const float* ybase = Y + ((size_t)b * NPTS + (size_t)seg * SEG_LEN) * 3;
    for (int i = threadIdx.x; i < SEG_LEN; i += RPB) {
        const float y0 = ybase[i * 3 + 0];
        const float y1 = ybase[i * 3 + 1];
        const float y2 = ybase[i * 3 + 2];
        ys[i] = make_float4(y0, y1, y2, fmaf(y0, y0, fmaf(y1, y1, y2 * y2)));
    }
    __syncthreads();

    // Load ROWS X points per thread; precompute -2x and |x|^2.
    float nx0[ROWS], nx1[ROWS], nx2[ROWS], hx[ROWS], acc[ROWS];
    const int rowBase = rowChunk * ROWS_PER_BLOCK + threadIdx.x;
    #pragma unroll
    for (int r = 0; r < ROWS; ++r) {
        const float* xp = X + ((size_t)b * NPTS + rowBase + r * RPB) * 3;
        const float x0 = xp[0], x1 = xp[1], x2 = xp[2];
        nx0[r] = -2.0f * x0;
        nx1[r] = -2.0f * x1;
        nx2[r] = -2.0f * x2;
        hx[r]  = fmaf(x0, x0, fmaf(x1, x1, x2 * x2));
        acc[r] = 3.4e38f;
    }

    #pragma unroll 4
    for (int j = 0; j < SEG_LEN; ++j) {
        const float4 y = ys[j];   // broadcast ds_read_b128, conflict-free
        #pragma unroll
        for (int r = 0; r < ROWS; ++r) {
            const float q = fmaf(nx0[r], y.x,
                            fmaf(nx1[r], y.y,
                            fmaf(nx2[r], y.z, y.w)));
            acc[r] = fminf(acc[r], q);   // 4 independent fmin chains
        }
    }

    // d^2 = q_min + |x|^2, clamped >= 0 so the uint bit-pattern ordering holds.
    unsigned int* base = mins + (size_t)dir * BATCH * NPTS + (size_t)b * NPTS;
    #pragma unroll
    for (int r = 0; r < ROWS; ++r) {
        const float d2 = fmaxf(acc[r] + hx[r], 0.0f);
        atomicMin(&base[rowBase + r * RPB], __float_as_uint(d2));
    }
}

// Single block, 1024 threads: sqrt the 2*B*N mins, sum, normalize.
// With N == M: mean_b(term1 + term2) = (sum of all sqrt mins) / (B*N).
__global__ __launch_bounds__(1024) void ahd_reduce_kernel(
    const unsigned int* __restrict__ mins, float* __restrict__ out)
{
    const int total4 = (2 * BATCH * NPTS) / 4;   // 8192 uint4
    const uint4* m4 = (const uint4*)mins;
    float s = 0.f;
    for (int i = threadIdx.x; i < total4; i += 1024) {
        const uint4 v = m4[i];
        s += sqrtf(__uint_as_float(v.x)) + sqrtf(__uint_as_float(v.y))
           + sqrtf(__uint_as_float(v.z)) + sqrtf(__uint_as_float(v.w));
    }

    #pragma unroll
    for (int off = 32; off > 0; off >>= 1)
        s += __shfl_down(s, off, 64);

    __shared__ float ws[16];
    const int lane = threadIdx.x & 63;
    const int w    = threadIdx.x >> 6;
    if (lane == 0) ws[w] = s;
    __syncthreads();
    if (threadIdx.x < 16) {                 // all in wave 0
        float t = ws[threadIdx.x];
        #pragma unroll
        for (int off = 8; off > 0; off >>= 1)
            t += __shfl_down(t, off, 64);
        if (threadIdx.x == 0)
            out[0] = t * (1.0f / (float)(BATCH * NPTS));
    }
}

extern "C" void kernel_launch(void* const* d_in, const int* in_sizes, int n_in,
                              void* d_out, int out_size, void* d_ws, size_t ws_size,
                              hipStream_t stream) {
    const float* set1 = (const float*)d_in[0];
    const float* set2 = (const float*)d_in[1];
    float* out = (float*)d_out;
    unsigned int* mins = (unsigned int*)d_ws;   // 2*BATCH*NPTS uints = 128 KB

    const size_t min_bytes = (size_t)2 * BATCH * NPTS * sizeof(unsigned int);
    // 0xFFFFFFFF == uint max -> +inf for the uint atomicMin.
    hipMemsetAsync(mins, 0xFF, min_bytes, stream);

    dim3 grid(CHUNKS * SEGS, BATCH, 2);
    ahd_min_kernel<<<grid, dim3(RPB), 0, stream>>>(set1, set2, mins);
    ahd_reduce_kernel<<<1, dim3(1024), 0, stream>>>(mins, out);
}

// Round 3
// 24.649 us; speedup vs baseline: 4.9752x; 1.1089x over previous
//
#include <hip/hip_runtime.h>
#include <math.h>

// Problem shape (fixed by setup_inputs): B=4, N=M=4096, D=3, fp32.
#define BATCH 4
#define NPTS  4096
#define RPB   256                 // threads per block
#define ROWS  4                   // rows (X points) per thread
#define ROWS_PER_BLOCK (RPB * ROWS)          // 1024
#define CHUNKS (NPTS / ROWS_PER_BLOCK)       // 4 row-chunks
#define SEGS  32                  // m-split -> 4*32*4*2 = 1024 blocks (4/CU)
#define SEG_LEN (NPTS / SEGS)     // 128 Y points staged per block

#define RED_BLOCKS 128            // kernel-2 grid (128*256 = 32768 = one thread/row)
#define FP_SCALE   268435456.0    // 2^28 fixed-point scale for deterministic sum

// ws layout: [0..8) u64 fixed-point total | [8..12) u32 arrival counter |
//            [64 ..) float part[2][BATCH][SEGS][NPTS]  (4 MB)

// Gram-form partial min over one Y segment; non-atomic store (each slot
// written exactly once -> no init pass, no atomics, no memset dispatch).
__global__ __launch_bounds__(RPB) void ahd_min_kernel(
    const float* __restrict__ set1, const float* __restrict__ set2,
    float* __restrict__ part, unsigned long long* __restrict__ total,
    unsigned int* __restrict__ counter)
{
    // One designated thread re-inits kernel-2's accumulators every call
    // (kernel boundary orders this before any kernel-2 read).
    if (blockIdx.x == 0 && blockIdx.y == 0 && blockIdx.z == 0 && threadIdx.x == 0) {
        *total = 0ULL;
        *counter = 0u;
    }

    const int dir      = blockIdx.z;
    const int b        = blockIdx.y;
    const int rowChunk = blockIdx.x / SEGS;
    const int seg      = blockIdx.x % SEGS;

    const float* __restrict__ X = dir ? set2 : set1;
    const float* __restrict__ Y = dir ? set1 : set2;

    __shared__ float4 ys[SEG_LEN];   // {y0, y1, y2, |y|^2}

    const float* ybase = Y + ((size_t)b * NPTS + (size_t)seg * SEG_LEN) * 3;
    for (int i = threadIdx.x; i < SEG_LEN; i += RPB) {
        const float y0 = ybase[i * 3 + 0];
        const float y1 = ybase[i * 3 + 1];
        const float y2 = ybase[i * 3 + 2];
        ys[i] = make_float4(y0, y1, y2, fmaf(y0, y0, fmaf(y1, y1, y2 * y2)));
    }
    __syncthreads();

    float nx0[ROWS], nx1[ROWS], nx2[ROWS], hx[ROWS], acc[ROWS];
    const int rowBase = rowChunk * ROWS_PER_BLOCK + threadIdx.x;
    #pragma unroll
    for (int r = 0; r < ROWS; ++r) {
        const float* xp = X + ((size_t)b * NPTS + rowBase + r * RPB) * 3;
        const float x0 = xp[0], x1 = xp[1], x2 = xp[2];
        nx0[r] = -2.0f * x0;
        nx1[r] = -2.0f * x1;
        nx2[r] = -2.0f * x2;
        hx[r]  = fmaf(x0, x0, fmaf(x1, x1, x2 * x2));
        acc[r] = 3.4e38f;
    }

    #pragma unroll 4
    for (int j = 0; j < SEG_LEN; ++j) {
        const float4 y = ys[j];   // broadcast ds_read_b128, conflict-free
        #pragma unroll
        for (int r = 0; r < ROWS; ++r) {
            const float q = fmaf(nx0[r], y.x,
                            fmaf(nx1[r], y.y,
                            fmaf(nx2[r], y.z, y.w)));
            acc[r] = fminf(acc[r], q);   // 4 independent fmin chains
        }
    }

    // partial d^2 for this segment, clamped >= 0; coalesced plain stores
    float* dst = part + (((size_t)(dir * BATCH + b) * SEGS + seg) * NPTS);
    #pragma unroll
    for (int r = 0; r < ROWS; ++r)
        dst[rowBase + r * RPB] = fmaxf(acc[r] + hx[r], 0.0f);
}

// Kernel 2: per row min over SEGS partials, sqrt, deterministic fixed-point
// sum via one u64 atomic; last-arriving block finalizes out[0].
__global__ __launch_bounds__(RPB) void ahd_reduce_kernel(
    const float* __restrict__ part, unsigned long long* __restrict__ total,
    unsigned int* __restrict__ counter, float* __restrict__ out)
{
    const int g    = blockIdx.x * RPB + threadIdx.x;   // 0..32767
    const int dirb = g >> 12;                          // which [dir][b] plane
    const int n    = g & (NPTS - 1);

    const float* p = part + ((size_t)dirb * SEGS) * NPTS + n;
    float m = p[0];
    #pragma unroll
    for (int s = 1; s < SEGS; ++s)
        m = fminf(m, p[(size_t)s * NPTS]);             // coalesced per seg

    float d = sqrtf(m);

    // wave tree-sum (deterministic order)
    #pragma unroll
    for (int off = 32; off > 0; off >>= 1)
        d += __shfl_down(d, off, 64);

    __shared__ unsigned long long ws[4];
    const int lane = threadIdx.x & 63;
    const int w    = threadIdx.x >> 6;
    if (lane == 0)
        ws[w] = (unsigned long long)((double)d * FP_SCALE);
    __syncthreads();

    if (threadIdx.x == 0) {
        const unsigned long long bs = ws[0] + ws[1] + ws[2] + ws[3];
        atomicAdd(total, bs);
        __threadfence();
        const unsigned int cnt = atomicAdd(counter, 1u);
        if (cnt == (unsigned int)(gridDim.x - 1)) {
            // last arriver: all total-adds are visible (fence + counter order)
            const unsigned long long fin = atomicAdd(total, 0ULL);
            out[0] = (float)((double)fin * (1.0 / FP_SCALE)
                             * (1.0 / (double)(BATCH * NPTS)));
        }
    }
}

extern "C" void kernel_launch(void* const* d_in, const int* in_sizes, int n_in,
                              void* d_out, int out_size, void* d_ws, size_t ws_size,
                              hipStream_t stream) {
    const float* set1 = (const float*)d_in[0];
    const float* set2 = (const float*)d_in[1];
    float* out = (float*)d_out;

    unsigned long long* total = (unsigned long long*)d_ws;
    unsigned int* counter = (unsigned int*)((char*)d_ws + 8);
    float* part = (float*)((char*)d_ws + 64);   // 2*BATCH*SEGS*NPTS floats = 4 MB

    dim3 grid(CHUNKS * SEGS, BATCH, 2);
    ahd_min_kernel<<<grid, dim3(RPB), 0, stream>>>(set1, set2, part, total, counter);
    ahd_reduce_kernel<<<RED_BLOCKS, dim3(RPB), 0, stream>>>(part, total, counter, out);
}